// Round 8
// baseline (358.464 us; speedup 1.0000x reference)
//
#include <hip/hip_runtime.h>
#include <math.h>

#define D_MODEL 768
#define NUM_HEADS 12
#define HEAD_DIM 64
#define SEQ 2048
#define BATCH 4
#define MROWS (BATCH * SEQ)   // 8192
#define HALF_D (D_MODEL / 2)  // 384

typedef __bf16 bf16x8 __attribute__((ext_vector_type(8)));
typedef __bf16 bf16x4 __attribute__((ext_vector_type(4)));
typedef float  f32x4  __attribute__((ext_vector_type(4)));

// async global->LDS, 16B per lane; LDS dest = wave-uniform base + lane*16
__device__ __forceinline__ void gload_lds16(const void* gp, void* lp) {
    __builtin_amdgcn_global_load_lds(
        (const __attribute__((address_space(1))) unsigned int*)gp,
        (__attribute__((address_space(3))) unsigned int*)lp, 16, 0, 0);
}

// ---------------------------------------------------------------------------
// RoPE table: tab[s][j] = (cos, sin). Transcendental calls only here.
// ---------------------------------------------------------------------------
__global__ __launch_bounds__(256)
void rope_table(float2* __restrict__ tab)
{
    int idx = blockIdx.x * 256 + threadIdx.x;      // s*384 + j
    int s = idx / HALF_D;
    int j = idx - s * HALF_D;
    float freq = __expf(-(float)j * (9.210340371976184f / 384.0f));
    float ang  = (float)s * freq;
    float sn, cs;
    sincosf(ang, &sn, &cs);
    tab[idx] = make_float2(cs, sn);
}

// ---------------------------------------------------------------------------
// Cast X fp32 -> bf16 row-major
// ---------------------------------------------------------------------------
__global__ __launch_bounds__(256)
void cast_x(const float* __restrict__ X, __bf16* __restrict__ Xb)
{
    size_t i = ((size_t)blockIdx.x * 256 + threadIdx.x) * 8;
    float4 u = *(const float4*)(X + i);
    float4 v = *(const float4*)(X + i + 4);
    bf16x8 o;
    o[0]=(__bf16)u.x; o[1]=(__bf16)u.y; o[2]=(__bf16)u.z; o[3]=(__bf16)u.w;
    o[4]=(__bf16)v.x; o[5]=(__bf16)v.y; o[6]=(__bf16)v.z; o[7]=(__bf16)v.w;
    *(bf16x8*)(Xb + i) = o;
}

// ---------------------------------------------------------------------------
// Cast + transpose weights: Wt[n][k] = (bf16)W[k][n].
// ---------------------------------------------------------------------------
__global__ __launch_bounds__(256)
void wcast(const float* __restrict__ W0, const float* __restrict__ W1,
           const float* __restrict__ W2, const float* __restrict__ W3,
           __bf16* __restrict__ T0, __bf16* __restrict__ T1,
           __bf16* __restrict__ T2, __bf16* __restrict__ T3)
{
    __shared__ float t[64][65];
    const int z = blockIdx.z;
    const float* W = z == 0 ? W0 : z == 1 ? W1 : z == 2 ? W2 : W3;
    __bf16*      T = z == 0 ? T0 : z == 1 ? T1 : z == 2 ? T2 : T3;

    const int tid = threadIdx.x;
    const int r0 = blockIdx.y * 64, c0 = blockIdx.x * 64;
    const int lx = tid & 63, g = tid >> 6;

    #pragma unroll
    for (int rr = 0; rr < 16; ++rr) {
        int r = g * 16 + rr;
        t[r][lx] = W[(size_t)(r0 + r) * D_MODEL + c0 + lx];
    }
    __syncthreads();

    const int n  = tid >> 2;
    const int kb = (tid & 3) * 16;
    bf16x8 o1, o2;
    #pragma unroll
    for (int m = 0; m < 8; ++m) o1[m] = (__bf16)t[kb + m][n];
    #pragma unroll
    for (int m = 0; m < 8; ++m) o2[m] = (__bf16)t[kb + 8 + m][n];
    __bf16* dst = T + (size_t)(c0 + n) * D_MODEL + r0 + kb;
    *(bf16x8*)dst       = o1;
    *(bf16x8*)(dst + 8) = o2;
}

// ---------------------------------------------------------------------------
// Fused QKV projection v2: BARRIER-FREE direct-register GEMM.
// Global layouts (row-major X, transposed W) already match MFMA fragment
// layouts, so each wave loads its own A/B frags straight to VGPRs
// (2x cross-wave redundancy -> L1). Two-phase software pipeline, no LDS,
// no __syncthreads -> waves free-run (R7 showed the LDS+barrier structure
// pinned at ~311 TF regardless of double-buffering).
// ---------------------------------------------------------------------------
__global__ __launch_bounds__(256)
void qkv_gemm(const __bf16* __restrict__ Xb,
              const __bf16* __restrict__ Wqt, const __bf16* __restrict__ Wkt,
              const __bf16* __restrict__ Wvt,
              const float* __restrict__ bq, const float* __restrict__ bk,
              const float* __restrict__ bv,
              const float2* __restrict__ tab,
              __bf16* __restrict__ Qb, __bf16* __restrict__ Kb,
              __bf16* __restrict__ Vtb)
{
    const int tid  = threadIdx.x;
    const int wv   = tid >> 6;
    const int ln   = tid & 63;
    const int t15  = ln & 15;
    const int quad = ln >> 4;
    const int wr = wv >> 1, wc = wv & 1;

    const int which = blockIdx.x / 6;            // 0=Q 1=K 2=V
    const int col0  = (blockIdx.x % 6) * 128;
    const int row0  = blockIdx.y * 128;

    const __bf16* Wt  = which == 0 ? Wqt : which == 1 ? Wkt : Wvt;
    const float* bias = which == 0 ? bq  : which == 1 ? bk  : bv;

    // per-wave fragment sources (lane-exact MFMA layout)
    const __bf16* Abase = Xb + (size_t)(row0 + 64 * wr + t15) * D_MODEL + 8 * quad;
    const __bf16* Bbase = Wt + (size_t)(col0 + 64 * wc + t15) * D_MODEL + 8 * quad;

    f32x4 acc[4][4];
    #pragma unroll
    for (int i = 0; i < 4; ++i)
        #pragma unroll
        for (int j = 0; j < 4; ++j) acc[i][j] = (f32x4){0.f,0.f,0.f,0.f};

    bf16x8 af[2][4], bfr[2][4];
    #pragma unroll
    for (int i = 0; i < 4; ++i) {
        af[0][i]  = *(const bf16x8*)(Abase + (size_t)(16 * i) * D_MODEL);
        bfr[0][i] = *(const bf16x8*)(Bbase + (size_t)(16 * i) * D_MODEL);
    }

    #pragma unroll
    for (int s = 0; s < 24; ++s) {           // 24 x 32-K steps, 2-phase pipeline
        const int cur = s & 1, nxt = cur ^ 1;
        if (s + 1 < 24) {
            const int kn = (s + 1) * 32;
            #pragma unroll
            for (int i = 0; i < 4; ++i) {
                af[nxt][i]  = *(const bf16x8*)(Abase + (size_t)(16 * i) * D_MODEL + kn);
                bfr[nxt][i] = *(const bf16x8*)(Bbase + (size_t)(16 * i) * D_MODEL + kn);
            }
        }
        #pragma unroll
        for (int i = 0; i < 4; ++i)
            #pragma unroll
            for (int j = 0; j < 4; ++j)
                acc[i][j] = __builtin_amdgcn_mfma_f32_16x16x32_bf16(af[cur][i], bfr[cur][j], acc[i][j], 0, 0, 0);
    }

    #pragma unroll
    for (int i = 0; i < 4; ++i) {
        const int rowb = row0 + 64 * wr + 16 * i + 4 * quad;
        #pragma unroll
        for (int j = 0; j < 4; ++j) {
            const int col = col0 + 64 * wc + 16 * j + t15;
            const float bval = bias[col];
            if (which < 2) {
                const int jh  = col >> 1;
                const float sgn = (col & 1) ? 1.0f : -1.0f;
                const float oscale = (which == 0) ? 0.125f : 1.0f;  // fold 1/sqrt(64) into Q
                __bf16* dst = (which ? Kb : Qb);
                #pragma unroll
                for (int r = 0; r < 4; ++r) {
                    const int rw = rowb + r;
                    const int s  = rw & (SEQ - 1);
                    float val  = acc[i][j][r] + bval;
                    float part = __shfl_xor(val, 1, 64);
                    float2 cs  = tab[(size_t)s * HALF_D + jh];
                    dst[(size_t)rw * D_MODEL + col] = (__bf16)((val * cs.x + part * sgn * cs.y) * oscale);
                }
            } else {
                const int h = col >> 6, d = col & 63;
                const int bidx = rowb >> 11, s = rowb & (SEQ - 1);
                bf16x4 pk;
                #pragma unroll
                for (int r = 0; r < 4; ++r) pk[r] = (__bf16)(acc[i][j][r] + bval);
                *(bf16x4*)(Vtb + ((size_t)(bidx * NUM_HEADS + h) * 64 + d) * SEQ + s) = pk;
            }
        }
    }
}

// ---------------------------------------------------------------------------
// Output projection v2: barrier-free direct-register GEMM, 64x128 tile
// (grid 768 = 3 blocks/CU). Each wave: 64 rows x 32 cols, 8 MFMA/step.
// ---------------------------------------------------------------------------
__global__ __launch_bounds__(256)
void out_gemm(const __bf16* __restrict__ Ab, const __bf16* __restrict__ Wt,
              const float* __restrict__ bias, float* __restrict__ Cout)
{
    const int tid  = threadIdx.x;
    const int wv   = tid >> 6;          // 0..3 -> col strip 32*wv
    const int ln   = tid & 63;
    const int t15  = ln & 15;
    const int quad = ln >> 4;

    const int col0 = blockIdx.x * 128;  // 6 col tiles
    const int row0 = blockIdx.y * 64;   // 128 row tiles

    const __bf16* Abase = Ab + (size_t)(row0 + t15) * D_MODEL + 8 * quad;
    const __bf16* Bbase = Wt + (size_t)(col0 + 32 * wv + t15) * D_MODEL + 8 * quad;

    f32x4 acc[4][2];
    #pragma unroll
    for (int i = 0; i < 4; ++i)
        #pragma unroll
        for (int j = 0; j < 2; ++j) acc[i][j] = (f32x4){0.f,0.f,0.f,0.f};

    bf16x8 af[2][4], bfr[2][2];
    #pragma unroll
    for (int i = 0; i < 4; ++i)
        af[0][i]  = *(const bf16x8*)(Abase + (size_t)(16 * i) * D_MODEL);
    #pragma unroll
    for (int j = 0; j < 2; ++j)
        bfr[0][j] = *(const bf16x8*)(Bbase + (size_t)(16 * j) * D_MODEL);

    #pragma unroll
    for (int s = 0; s < 24; ++s) {
        const int cur = s & 1, nxt = cur ^ 1;
        if (s + 1 < 24) {
            const int kn = (s + 1) * 32;
            #pragma unroll
            for (int i = 0; i < 4; ++i)
                af[nxt][i]  = *(const bf16x8*)(Abase + (size_t)(16 * i) * D_MODEL + kn);
            #pragma unroll
            for (int j = 0; j < 2; ++j)
                bfr[nxt][j] = *(const bf16x8*)(Bbase + (size_t)(16 * j) * D_MODEL + kn);
        }
        #pragma unroll
        for (int i = 0; i < 4; ++i)
            #pragma unroll
            for (int j = 0; j < 2; ++j)
                acc[i][j] = __builtin_amdgcn_mfma_f32_16x16x32_bf16(af[cur][i], bfr[cur][j], acc[i][j], 0, 0, 0);
    }

    #pragma unroll
    for (int i = 0; i < 4; ++i) {
        const int rowb = row0 + 16 * i + 4 * quad;
        #pragma unroll
        for (int j = 0; j < 2; ++j) {
            const int col = col0 + 32 * wv + 16 * j + t15;
            const float bval = bias[col];
            #pragma unroll
            for (int r = 0; r < 4; ++r)
                Cout[(size_t)(rowb + r) * D_MODEL + col] = acc[i][j][r] + bval;
        }
    }
}

// ---------------------------------------------------------------------------
// Flash attention v3 (unchanged from R6): 128-query blocks, 8 waves, no-max
// softmax, lane-local l, double-buffered K/V, P as bf16 via per-wave LDS.
// ---------------------------------------------------------------------------
__device__ __forceinline__ void attn_tile(
    const bf16x8 (*Kbuf)[64], const bf16x8 (*Vbuf)[64],
    __bf16 (*Psw)[72],
    bf16x8 aq0, bf16x8 aq1,
    f32x4* o, float* lacc,
    int ln, int t15, int quad, int j0, int qabs, bool domask)
{
    f32x4 s[4];
    #pragma unroll
    for (int c = 0; c < 4; ++c) {
        s[c] = (f32x4){0.f, 0.f, 0.f, 0.f};
        s[c] = __builtin_amdgcn_mfma_f32_16x16x32_bf16(aq0, Kbuf[c][ln],     s[c], 0, 0, 0);
        s[c] = __builtin_amdgcn_mfma_f32_16x16x32_bf16(aq1, Kbuf[4 + c][ln], s[c], 0, 0, 0);
    }

    float p[4][4];
    #pragma unroll
    for (int c = 0; c < 4; ++c)
        #pragma unroll
        for (int r = 0; r < 4; ++r) {
            float e = __expf(s[c][r]);
            if (domask && (j0 + 16 * c + t15 > qabs + r)) e = 0.f;
            p[c][r] = e;
            lacc[r] += e;
        }

    #pragma unroll
    for (int c = 0; c < 4; ++c)
        #pragma unroll
        for (int r = 0; r < 4; ++r)
            Psw[4 * quad + r][16 * c + t15] = (__bf16)p[c][r];
    __asm__ volatile("s_waitcnt lgkmcnt(0)" ::: "memory");

    bf16x8 ap0 = *(const bf16x8*)&Psw[t15][8 * quad];
    bf16x8 ap1 = *(const bf16x8*)&Psw[t15][32 + 8 * quad];

    #pragma unroll
    for (int c = 0; c < 4; ++c) {
        o[c] = __builtin_amdgcn_mfma_f32_16x16x32_bf16(ap0, Vbuf[c][ln],     o[c], 0, 0, 0);
        o[c] = __builtin_amdgcn_mfma_f32_16x16x32_bf16(ap1, Vbuf[4 + c][ln], o[c], 0, 0, 0);
    }
}

__global__ __launch_bounds__(512)
void attn_flash(const __bf16* __restrict__ Q, const __bf16* __restrict__ K,
                const __bf16* __restrict__ Vt, __bf16* __restrict__ O)
{
    __shared__ bf16x8 Kf[2][8][64];     // 16 KB (double-buffered)
    __shared__ bf16x8 Vf[2][8][64];     // 16 KB
    __shared__ __bf16 Psb[8][16][72];   // 18.4 KB

    const int tid  = threadIdx.x;
    const int wv   = tid >> 6;
    const int ln   = tid & 63;
    const int t15  = ln & 15;
    const int quad = ln >> 4;

    const int n  = blockIdx.x;
    const int sb = n >> 8;
    const int tb = n & 255;
    const int a  = tb & 15;
    const int qt = (sb == 0) ? a : (sb == 1) ? (15 - a) : ((a + 8) & 15);
    const int bh = (tb >> 4) + 16 * sb;
    const int b  = bh / NUM_HEADS;
    const int h  = bh % NUM_HEADS;
    const int q0 = qt * 128;
    const int nt = (q0 >> 6) + 2;

    bf16x8 aq0, aq1;
    {
        const __bf16* qs = Q + (size_t)(b * SEQ + q0 + 16 * wv + t15) * D_MODEL + h * 64 + 8 * quad;
        aq0 = *(const bf16x8*)qs;
        aq1 = *(const bf16x8*)(qs + 32);
    }

    const __bf16* kp = K  + ((size_t)b * SEQ + 16 * (wv & 3) + t15) * D_MODEL
                          + h * 64 + 32 * (wv >> 2) + 8 * quad;
    const __bf16* vp = Vt + ((size_t)bh * 64 + 16 * (wv & 3) + t15) * SEQ
                          + 32 * (wv >> 2) + 8 * quad;

    f32x4 o[4];
    #pragma unroll
    for (int c = 0; c < 4; ++c) o[c] = (f32x4){0.f,0.f,0.f,0.f};
    float lacc[4] = {0.f, 0.f, 0.f, 0.f};
    const int qabs = q0 + 16 * wv + 4 * quad;

    gload_lds16(kp, &Kf[0][wv][0]);
    gload_lds16(vp, &Vf[0][wv][0]);

    int cur = 0;
    for (int it = 0; it < nt; ++it) {
        __syncthreads();
        if (it + 1 < nt) {
            const int jn = (it + 1) * 64;
            gload_lds16(kp + (size_t)jn * D_MODEL, &Kf[cur ^ 1][wv][0]);
            gload_lds16(vp + jn,                   &Vf[cur ^ 1][wv][0]);
        }
        const int j0 = it * 64;
        const bool domask = (j0 + 63) > (q0 + 16 * wv);
        attn_tile(Kf[cur], Vf[cur], Psb[wv], aq0, aq1, o, lacc,
                  ln, t15, quad, j0, qabs, domask);
        cur ^= 1;
    }

    #pragma unroll
    for (int off = 1; off < 16; off <<= 1)
        #pragma unroll
        for (int r = 0; r < 4; ++r)
            lacc[r] += __shfl_xor(lacc[r], off, 64);

    float inv[4];
    #pragma unroll
    for (int r = 0; r < 4; ++r) inv[r] = 1.0f / lacc[r];
    #pragma unroll
    for (int c = 0; c < 4; ++c)
        #pragma unroll
        for (int r = 0; r < 4; ++r) {
            int row = qabs + r;
            O[(size_t)(b * SEQ + row) * D_MODEL + h * 64 + 16 * c + t15] = (__bf16)(o[c][r] * inv[r]);
        }
}

// ---------------------------------------------------------------------------
extern "C" void kernel_launch(void* const* d_in, const int* in_sizes, int n_in,
                              void* d_out, int out_size, void* d_ws, size_t ws_size,
                              hipStream_t stream) {
    const float* X  = (const float*)d_in[0];
    const float* Wq = (const float*)d_in[1];
    const float* bq = (const float*)d_in[2];
    const float* Wk = (const float*)d_in[3];
    const float* bk = (const float*)d_in[4];
    const float* Wv = (const float*)d_in[5];
    const float* bv = (const float*)d_in[6];
    const float* Wo = (const float*)d_in[7];
    const float* bo = (const float*)d_in[8];
    float* out = (float*)d_out;

    const size_t BSD = (size_t)MROWS * D_MODEL;   // 6,291,456
    const size_t WSZ = (size_t)D_MODEL * D_MODEL; //   589,824

    __bf16* Xb  = (__bf16*)d_ws;
    __bf16* Qb  = Xb  + BSD;
    __bf16* Kb  = Qb  + BSD;
    __bf16* Vtb = Kb  + BSD;
    __bf16* Ob  = Vtb + BSD;
    __bf16* Wqt = Ob  + BSD;
    __bf16* Wkt = Wqt + WSZ;
    __bf16* Wvt = Wkt + WSZ;
    __bf16* Wot = Wvt + WSZ;
    float2* Tab = (float2*)(Wot + WSZ);

    rope_table<<<(SEQ * HALF_D) / 256, 256, 0, stream>>>(Tab);
    cast_x<<<BSD / (256 * 8), 256, 0, stream>>>(X, Xb);
    wcast<<<dim3(12, 12, 4), 256, 0, stream>>>(Wq, Wk, Wv, Wo, Wqt, Wkt, Wvt, Wot);

    qkv_gemm<<<dim3(18, 64), 256, 0, stream>>>(Xb, Wqt, Wkt, Wvt, bq, bk, bv, Tab, Qb, Kb, Vtb);

    attn_flash<<<768, 512, 0, stream>>>(Qb, Kb, Vtb, Ob);

    out_gemm<<<dim3(6, 128), 256, 0, stream>>>(Ob, Wot, bo, out);
}

// Round 9
// 275.064 us; speedup vs baseline: 1.3032x; 1.3032x over previous
//
#include <hip/hip_runtime.h>
#include <math.h>

#define D_MODEL 768
#define NUM_HEADS 12
#define HEAD_DIM 64
#define SEQ 2048
#define BATCH 4
#define MROWS (BATCH * SEQ)   // 8192
#define HALF_D (D_MODEL / 2)  // 384

typedef __bf16 bf16x8 __attribute__((ext_vector_type(8)));
typedef __bf16 bf16x4 __attribute__((ext_vector_type(4)));
typedef float  f32x4  __attribute__((ext_vector_type(4)));

// async global->LDS, 16B per lane; LDS dest = wave-uniform base + lane*16
__device__ __forceinline__ void gload_lds16(const void* gp, void* lp) {
    __builtin_amdgcn_global_load_lds(
        (const __attribute__((address_space(1))) unsigned int*)gp,
        (__attribute__((address_space(3))) unsigned int*)lp, 16, 0, 0);
}

// ---------------------------------------------------------------------------
// RoPE table: tab[s][j] = (cos, sin). Transcendental calls only here.
// ---------------------------------------------------------------------------
__global__ __launch_bounds__(256)
void rope_table(float2* __restrict__ tab)
{
    int idx = blockIdx.x * 256 + threadIdx.x;      // s*384 + j
    int s = idx / HALF_D;
    int j = idx - s * HALF_D;
    float freq = __expf(-(float)j * (9.210340371976184f / 384.0f));
    float ang  = (float)s * freq;
    float sn, cs;
    sincosf(ang, &sn, &cs);
    tab[idx] = make_float2(cs, sn);
}

// ---------------------------------------------------------------------------
// Cast X fp32 -> bf16 row-major
// ---------------------------------------------------------------------------
__global__ __launch_bounds__(256)
void cast_x(const float* __restrict__ X, __bf16* __restrict__ Xb)
{
    size_t i = ((size_t)blockIdx.x * 256 + threadIdx.x) * 8;
    float4 u = *(const float4*)(X + i);
    float4 v = *(const float4*)(X + i + 4);
    bf16x8 o;
    o[0]=(__bf16)u.x; o[1]=(__bf16)u.y; o[2]=(__bf16)u.z; o[3]=(__bf16)u.w;
    o[4]=(__bf16)v.x; o[5]=(__bf16)v.y; o[6]=(__bf16)v.z; o[7]=(__bf16)v.w;
    *(bf16x8*)(Xb + i) = o;
}

// ---------------------------------------------------------------------------
// Cast + transpose weights: Wt[n][k] = (bf16)W[k][n].
// ---------------------------------------------------------------------------
__global__ __launch_bounds__(256)
void wcast(const float* __restrict__ W0, const float* __restrict__ W1,
           const float* __restrict__ W2, const float* __restrict__ W3,
           __bf16* __restrict__ T0, __bf16* __restrict__ T1,
           __bf16* __restrict__ T2, __bf16* __restrict__ T3)
{
    __shared__ float t[64][65];
    const int z = blockIdx.z;
    const float* W = z == 0 ? W0 : z == 1 ? W1 : z == 2 ? W2 : W3;
    __bf16*      T = z == 0 ? T0 : z == 1 ? T1 : z == 2 ? T2 : T3;

    const int tid = threadIdx.x;
    const int r0 = blockIdx.y * 64, c0 = blockIdx.x * 64;
    const int lx = tid & 63, g = tid >> 6;

    #pragma unroll
    for (int rr = 0; rr < 16; ++rr) {
        int r = g * 16 + rr;
        t[r][lx] = W[(size_t)(r0 + r) * D_MODEL + c0 + lx];
    }
    __syncthreads();

    const int n  = tid >> 2;
    const int kb = (tid & 3) * 16;
    bf16x8 o1, o2;
    #pragma unroll
    for (int m = 0; m < 8; ++m) o1[m] = (__bf16)t[kb + m][n];
    #pragma unroll
    for (int m = 0; m < 8; ++m) o2[m] = (__bf16)t[kb + 8 + m][n];
    __bf16* dst = T + (size_t)(c0 + n) * D_MODEL + r0 + kb;
    *(bf16x8*)dst       = o1;
    *(bf16x8*)(dst + 8) = o2;
}

// ---------------------------------------------------------------------------
// Fused QKV projection v3: cooperative LDS staging (R8's direct-register
// variant regressed 1.8x - pooled global_load_lds staging wins), BK=64
// (32 MFMA per barrier-drain stall, 12 stalls/block vs 24), XCD-swizzled
// 1D grid: lin = c*64 + r -> XCD = r%8, so each XCD's X working set is
// 8 row-tiles (1.57 MB, L2-resident) reused by all 18 col-variants.
// ---------------------------------------------------------------------------
__global__ __launch_bounds__(256)
void qkv_gemm(const __bf16* __restrict__ Xb,
              const __bf16* __restrict__ Wqt, const __bf16* __restrict__ Wkt,
              const __bf16* __restrict__ Wvt,
              const float* __restrict__ bq, const float* __restrict__ bk,
              const float* __restrict__ bv,
              const float2* __restrict__ tab,
              __bf16* __restrict__ Qb, __bf16* __restrict__ Kb,
              __bf16* __restrict__ Vtb)
{
    __shared__ bf16x8 Asf[2][8][64];    // 16 KB: [kstep][rowblock][lane]
    __shared__ bf16x8 Bsf[2][8][64];    // 16 KB

    const int tid  = threadIdx.x;
    const int wv   = tid >> 6;
    const int ln   = tid & 63;
    const int t15  = ln & 15;
    const int quad = ln >> 4;
    const int wr = wv >> 1, wc = wv & 1;

    const int lin = blockIdx.x;          // 1152 blocks: c*64 + r
    const int c   = lin >> 6;            // 0..17
    const int r   = lin & 63;            // 0..63  (XCD = r % 8)
    const int which = c / 6;             // 0=Q 1=K 2=V
    const int col0  = (c % 6) * 128;
    const int row0  = r * 128;

    const __bf16* Wt  = which == 0 ? Wqt : which == 1 ? Wkt : Wvt;
    const float* bias = which == 0 ? bq  : which == 1 ? bk  : bv;

    f32x4 acc[4][4];
    #pragma unroll
    for (int i = 0; i < 4; ++i)
        #pragma unroll
        for (int j = 0; j < 4; ++j) acc[i][j] = (f32x4){0.f,0.f,0.f,0.f};

    // staging sources: wave wv stages A/B frags (ks, i) for i in {wv, wv+4}
    const __bf16* a0 = Xb + (size_t)(row0 + 16 * wv       + t15) * D_MODEL + 8 * quad;
    const __bf16* a1 = Xb + (size_t)(row0 + 16 * (wv + 4) + t15) * D_MODEL + 8 * quad;
    const __bf16* b0 = Wt + (size_t)(col0 + 16 * wv       + t15) * D_MODEL + 8 * quad;
    const __bf16* b1 = Wt + (size_t)(col0 + 16 * (wv + 4) + t15) * D_MODEL + 8 * quad;

    for (int k0 = 0; k0 < D_MODEL; k0 += 64) {
        __syncthreads();                 // protect prev-iter LDS reads
        #pragma unroll
        for (int ks = 0; ks < 2; ++ks) {
            const int kk = k0 + 32 * ks;
            gload_lds16(a0 + kk, &Asf[ks][wv][0]);
            gload_lds16(a1 + kk, &Asf[ks][wv + 4][0]);
            gload_lds16(b0 + kk, &Bsf[ks][wv][0]);
            gload_lds16(b1 + kk, &Bsf[ks][wv + 4][0]);
        }
        __syncthreads();                 // drain staging

        #pragma unroll
        for (int ks = 0; ks < 2; ++ks) {
            bf16x8 af[4], bfr[4];
            #pragma unroll
            for (int i = 0; i < 4; ++i) af[i]  = Asf[ks][4 * wr + i][ln];
            #pragma unroll
            for (int j = 0; j < 4; ++j) bfr[j] = Bsf[ks][4 * wc + j][ln];
            #pragma unroll
            for (int i = 0; i < 4; ++i)
                #pragma unroll
                for (int j = 0; j < 4; ++j)
                    acc[i][j] = __builtin_amdgcn_mfma_f32_16x16x32_bf16(af[i], bfr[j], acc[i][j], 0, 0, 0);
        }
    }

    #pragma unroll
    for (int i = 0; i < 4; ++i) {
        const int rowb = row0 + 64 * wr + 16 * i + 4 * quad;
        #pragma unroll
        for (int j = 0; j < 4; ++j) {
            const int col = col0 + 64 * wc + 16 * j + t15;
            const float bval = bias[col];
            if (which < 2) {
                const int jh  = col >> 1;
                const float sgn = (col & 1) ? 1.0f : -1.0f;
                const float oscale = (which == 0) ? 0.125f : 1.0f;  // fold 1/sqrt(64) into Q
                __bf16* dst = (which ? Kb : Qb);
                #pragma unroll
                for (int rr = 0; rr < 4; ++rr) {
                    const int rw = rowb + rr;
                    const int s  = rw & (SEQ - 1);
                    float val  = acc[i][j][rr] + bval;
                    float part = __shfl_xor(val, 1, 64);
                    float2 cs  = tab[(size_t)s * HALF_D + jh];
                    dst[(size_t)rw * D_MODEL + col] = (__bf16)((val * cs.x + part * sgn * cs.y) * oscale);
                }
            } else {
                const int h = col >> 6, d = col & 63;
                const int bidx = rowb >> 11, s = rowb & (SEQ - 1);
                bf16x4 pk;
                #pragma unroll
                for (int rr = 0; rr < 4; ++rr) pk[rr] = (__bf16)(acc[i][j][rr] + bval);
                *(bf16x4*)(Vtb + ((size_t)(bidx * NUM_HEADS + h) * 64 + d) * SEQ + s) = pk;
            }
        }
    }
}

// ---------------------------------------------------------------------------
// Output projection v3: same BK=64 cooperative structure, XCD-swizzled 1D
// grid (384 = c*64 + r), fp32 output + bias.
// ---------------------------------------------------------------------------
__global__ __launch_bounds__(256)
void out_gemm(const __bf16* __restrict__ Ab, const __bf16* __restrict__ Wt,
              const float* __restrict__ bias, float* __restrict__ Cout)
{
    __shared__ bf16x8 Asf[2][8][64];
    __shared__ bf16x8 Bsf[2][8][64];

    const int tid  = threadIdx.x;
    const int wv   = tid >> 6;
    const int ln   = tid & 63;
    const int t15  = ln & 15;
    const int quad = ln >> 4;
    const int wr = wv >> 1, wc = wv & 1;

    const int lin = blockIdx.x;          // 384 blocks: c*64 + r
    const int col0 = (lin >> 6) * 128;
    const int row0 = (lin & 63) * 128;

    f32x4 acc[4][4];
    #pragma unroll
    for (int i = 0; i < 4; ++i)
        #pragma unroll
        for (int j = 0; j < 4; ++j) acc[i][j] = (f32x4){0.f,0.f,0.f,0.f};

    const __bf16* a0 = Ab + (size_t)(row0 + 16 * wv       + t15) * D_MODEL + 8 * quad;
    const __bf16* a1 = Ab + (size_t)(row0 + 16 * (wv + 4) + t15) * D_MODEL + 8 * quad;
    const __bf16* b0 = Wt + (size_t)(col0 + 16 * wv       + t15) * D_MODEL + 8 * quad;
    const __bf16* b1 = Wt + (size_t)(col0 + 16 * (wv + 4) + t15) * D_MODEL + 8 * quad;

    for (int k0 = 0; k0 < D_MODEL; k0 += 64) {
        __syncthreads();
        #pragma unroll
        for (int ks = 0; ks < 2; ++ks) {
            const int kk = k0 + 32 * ks;
            gload_lds16(a0 + kk, &Asf[ks][wv][0]);
            gload_lds16(a1 + kk, &Asf[ks][wv + 4][0]);
            gload_lds16(b0 + kk, &Bsf[ks][wv][0]);
            gload_lds16(b1 + kk, &Bsf[ks][wv + 4][0]);
        }
        __syncthreads();

        #pragma unroll
        for (int ks = 0; ks < 2; ++ks) {
            bf16x8 af[4], bfr[4];
            #pragma unroll
            for (int i = 0; i < 4; ++i) af[i]  = Asf[ks][4 * wr + i][ln];
            #pragma unroll
            for (int j = 0; j < 4; ++j) bfr[j] = Bsf[ks][4 * wc + j][ln];
            #pragma unroll
            for (int i = 0; i < 4; ++i)
                #pragma unroll
                for (int j = 0; j < 4; ++j)
                    acc[i][j] = __builtin_amdgcn_mfma_f32_16x16x32_bf16(af[i], bfr[j], acc[i][j], 0, 0, 0);
        }
    }

    #pragma unroll
    for (int i = 0; i < 4; ++i) {
        const int rowb = row0 + 64 * wr + 16 * i + 4 * quad;
        #pragma unroll
        for (int j = 0; j < 4; ++j) {
            const int col = col0 + 64 * wc + 16 * j + t15;
            const float bval = bias[col];
            #pragma unroll
            for (int rr = 0; rr < 4; ++rr)
                Cout[(size_t)(rowb + rr) * D_MODEL + col] = acc[i][j][rr] + bval;
        }
    }
}

// ---------------------------------------------------------------------------
// Flash attention v3 (unchanged from R6): 128-query blocks, 8 waves, no-max
// softmax, lane-local l, double-buffered K/V, P as bf16 via per-wave LDS.
// ---------------------------------------------------------------------------
__device__ __forceinline__ void attn_tile(
    const bf16x8 (*Kbuf)[64], const bf16x8 (*Vbuf)[64],
    __bf16 (*Psw)[72],
    bf16x8 aq0, bf16x8 aq1,
    f32x4* o, float* lacc,
    int ln, int t15, int quad, int j0, int qabs, bool domask)
{
    f32x4 s[4];
    #pragma unroll
    for (int c = 0; c < 4; ++c) {
        s[c] = (f32x4){0.f, 0.f, 0.f, 0.f};
        s[c] = __builtin_amdgcn_mfma_f32_16x16x32_bf16(aq0, Kbuf[c][ln],     s[c], 0, 0, 0);
        s[c] = __builtin_amdgcn_mfma_f32_16x16x32_bf16(aq1, Kbuf[4 + c][ln], s[c], 0, 0, 0);
    }

    float p[4][4];
    #pragma unroll
    for (int c = 0; c < 4; ++c)
        #pragma unroll
        for (int r = 0; r < 4; ++r) {
            float e = __expf(s[c][r]);
            if (domask && (j0 + 16 * c + t15 > qabs + r)) e = 0.f;
            p[c][r] = e;
            lacc[r] += e;
        }

    #pragma unroll
    for (int c = 0; c < 4; ++c)
        #pragma unroll
        for (int r = 0; r < 4; ++r)
            Psw[4 * quad + r][16 * c + t15] = (__bf16)p[c][r];
    __asm__ volatile("s_waitcnt lgkmcnt(0)" ::: "memory");

    bf16x8 ap0 = *(const bf16x8*)&Psw[t15][8 * quad];
    bf16x8 ap1 = *(const bf16x8*)&Psw[t15][32 + 8 * quad];

    #pragma unroll
    for (int c = 0; c < 4; ++c) {
        o[c] = __builtin_amdgcn_mfma_f32_16x16x32_bf16(ap0, Vbuf[c][ln],     o[c], 0, 0, 0);
        o[c] = __builtin_amdgcn_mfma_f32_16x16x32_bf16(ap1, Vbuf[4 + c][ln], o[c], 0, 0, 0);
    }
}

__global__ __launch_bounds__(512)
void attn_flash(const __bf16* __restrict__ Q, const __bf16* __restrict__ K,
                const __bf16* __restrict__ Vt, __bf16* __restrict__ O)
{
    __shared__ bf16x8 Kf[2][8][64];     // 16 KB (double-buffered)
    __shared__ bf16x8 Vf[2][8][64];     // 16 KB
    __shared__ __bf16 Psb[8][16][72];   // 18.4 KB

    const int tid  = threadIdx.x;
    const int wv   = tid >> 6;
    const int ln   = tid & 63;
    const int t15  = ln & 15;
    const int quad = ln >> 4;

    const int n  = blockIdx.x;
    const int sb = n >> 8;
    const int tb = n & 255;
    const int a  = tb & 15;
    const int qt = (sb == 0) ? a : (sb == 1) ? (15 - a) : ((a + 8) & 15);
    const int bh = (tb >> 4) + 16 * sb;
    const int b  = bh / NUM_HEADS;
    const int h  = bh % NUM_HEADS;
    const int q0 = qt * 128;
    const int nt = (q0 >> 6) + 2;

    bf16x8 aq0, aq1;
    {
        const __bf16* qs = Q + (size_t)(b * SEQ + q0 + 16 * wv + t15) * D_MODEL + h * 64 + 8 * quad;
        aq0 = *(const bf16x8*)qs;
        aq1 = *(const bf16x8*)(qs + 32);
    }

    const __bf16* kp = K  + ((size_t)b * SEQ + 16 * (wv & 3) + t15) * D_MODEL
                          + h * 64 + 32 * (wv >> 2) + 8 * quad;
    const __bf16* vp = Vt + ((size_t)bh * 64 + 16 * (wv & 3) + t15) * SEQ
                          + 32 * (wv >> 2) + 8 * quad;

    f32x4 o[4];
    #pragma unroll
    for (int c = 0; c < 4; ++c) o[c] = (f32x4){0.f,0.f,0.f,0.f};
    float lacc[4] = {0.f, 0.f, 0.f, 0.f};
    const int qabs = q0 + 16 * wv + 4 * quad;

    gload_lds16(kp, &Kf[0][wv][0]);
    gload_lds16(vp, &Vf[0][wv][0]);

    int cur = 0;
    for (int it = 0; it < nt; ++it) {
        __syncthreads();
        if (it + 1 < nt) {
            const int jn = (it + 1) * 64;
            gload_lds16(kp + (size_t)jn * D_MODEL, &Kf[cur ^ 1][wv][0]);
            gload_lds16(vp + jn,                   &Vf[cur ^ 1][wv][0]);
        }
        const int j0 = it * 64;
        const bool domask = (j0 + 63) > (q0 + 16 * wv);
        attn_tile(Kf[cur], Vf[cur], Psb[wv], aq0, aq1, o, lacc,
                  ln, t15, quad, j0, qabs, domask);
        cur ^= 1;
    }

    #pragma unroll
    for (int off = 1; off < 16; off <<= 1)
        #pragma unroll
        for (int r = 0; r < 4; ++r)
            lacc[r] += __shfl_xor(lacc[r], off, 64);

    float inv[4];
    #pragma unroll
    for (int r = 0; r < 4; ++r) inv[r] = 1.0f / lacc[r];
    #pragma unroll
    for (int c = 0; c < 4; ++c)
        #pragma unroll
        for (int r = 0; r < 4; ++r) {
            int row = qabs + r;
            O[(size_t)(b * SEQ + row) * D_MODEL + h * 64 + 16 * c + t15] = (__bf16)(o[c][r] * inv[r]);
        }
}

// ---------------------------------------------------------------------------
extern "C" void kernel_launch(void* const* d_in, const int* in_sizes, int n_in,
                              void* d_out, int out_size, void* d_ws, size_t ws_size,
                              hipStream_t stream) {
    const float* X  = (const float*)d_in[0];
    const float* Wq = (const float*)d_in[1];
    const float* bq = (const float*)d_in[2];
    const float* Wk = (const float*)d_in[3];
    const float* bk = (const float*)d_in[4];
    const float* Wv = (const float*)d_in[5];
    const float* bv = (const float*)d_in[6];
    const float* Wo = (const float*)d_in[7];
    const float* bo = (const float*)d_in[8];
    float* out = (float*)d_out;

    const size_t BSD = (size_t)MROWS * D_MODEL;   // 6,291,456
    const size_t WSZ = (size_t)D_MODEL * D_MODEL; //   589,824

    __bf16* Xb  = (__bf16*)d_ws;
    __bf16* Qb  = Xb  + BSD;
    __bf16* Kb  = Qb  + BSD;
    __bf16* Vtb = Kb  + BSD;
    __bf16* Ob  = Vtb + BSD;
    __bf16* Wqt = Ob  + BSD;
    __bf16* Wkt = Wqt + WSZ;
    __bf16* Wvt = Wkt + WSZ;
    __bf16* Wot = Wvt + WSZ;
    float2* Tab = (float2*)(Wot + WSZ);

    rope_table<<<(SEQ * HALF_D) / 256, 256, 0, stream>>>(Tab);
    cast_x<<<BSD / (256 * 8), 256, 0, stream>>>(X, Xb);
    wcast<<<dim3(12, 12, 4), 256, 0, stream>>>(Wq, Wk, Wv, Wo, Wqt, Wkt, Wvt, Wot);

    qkv_gemm<<<1152, 256, 0, stream>>>(Xb, Wqt, Wkt, Wvt, bq, bk, bv, Tab, Qb, Kb, Vtb);

    attn_flash<<<768, 512, 0, stream>>>(Qb, Kb, Vtb, Ob);

    out_gemm<<<384, 256, 0, stream>>>(Ob, Wot, bo, out);
}